// Round 1
// baseline (94.651 us; speedup 1.0000x reference)
//
#include <hip/hip_runtime.h>
#include <hip/hip_bf16.h>

#define SEQ_L 512
#define EDIM 300
#define HDIM 512
#define ODIM 5
#define BATCH 1024

// ---------------- Kernel A: embedding gather + sum + length divide ----------
// One block per batch row. 256 threads = 4 waves. Tokens staged in LDS.
// Wave w handles tokens t = w, w+4, ... (128 each). Each lane accumulates a
// float4 slice of the 300-dim embedding (75 float4; lanes 0..63 take f4 idx
// `lane`, lanes 0..10 also take f4 idx `lane+64`).
__global__ __launch_bounds__(256) void embed_sum_kernel(
    const int* __restrict__ x, const float* __restrict__ weight,
    float* __restrict__ y) {
  const int b = blockIdx.x;
  __shared__ int stok[SEQ_L];
  __shared__ int s_minidx;
  __shared__ float sred[4][304];  // 4 waves x 300 dims (padded)

  const int tid = threadIdx.x;
  if (tid == 0) s_minidx = SEQ_L;

  const int tokA = x[b * SEQ_L + tid];
  const int tokB = x[b * SEQ_L + tid + 256];
  stok[tid] = tokA;
  stok[tid + 256] = tokB;
  __syncthreads();

  // first-zero index (only consumed when last token == 0)
  if (tokA == 0) atomicMin(&s_minidx, tid);
  if (tokB == 0) atomicMin(&s_minidx, tid + 256);

  const int wave = tid >> 6;
  const int lane = tid & 63;
  const bool has2 = lane < (75 - 64);  // f4 idx lane+64 < 75

  float4 acc0 = make_float4(0.f, 0.f, 0.f, 0.f);
  float4 acc1 = make_float4(0.f, 0.f, 0.f, 0.f);

  for (int t = wave; t < SEQ_L; t += 4) {
    const int tok = stok[t];
    const float4* row = reinterpret_cast<const float4*>(weight + (size_t)tok * EDIM);
    float4 v0 = row[lane];
    acc0.x += v0.x; acc0.y += v0.y; acc0.z += v0.z; acc0.w += v0.w;
    if (has2) {
      float4 v1 = row[lane + 64];
      acc1.x += v1.x; acc1.y += v1.y; acc1.z += v1.z; acc1.w += v1.w;
    }
  }

  // write per-wave partials to LDS
  {
    const int d0 = 4 * lane;
    sred[wave][d0 + 0] = acc0.x;
    sred[wave][d0 + 1] = acc0.y;
    sred[wave][d0 + 2] = acc0.z;
    sred[wave][d0 + 3] = acc0.w;
    if (has2) {
      const int d1 = 4 * (lane + 64);
      sred[wave][d1 + 0] = acc1.x;
      sred[wave][d1 + 1] = acc1.y;
      sred[wave][d1 + 2] = acc1.z;
      sred[wave][d1 + 3] = acc1.w;
    }
  }
  __syncthreads();

  const float length =
      (stok[SEQ_L - 1] != 0) ? (float)SEQ_L : (float)s_minidx;
  const float inv_len = 1.0f / length;

  // dims 0..299 handled by threads tid and tid+256 (tid < 44)
  for (int d = tid; d < EDIM; d += 256) {
    float s = sred[0][d] + sred[1][d] + sred[2][d] + sred[3][d];
    y[(size_t)b * EDIM + d] = s * inv_len;
  }
}

// ---------------- Kernel T: transpose w1 [512,300] -> w1t [300,512] ---------
__global__ __launch_bounds__(256) void transpose_kernel(
    const float* __restrict__ in, float* __restrict__ out) {
  // in[R=512][C=300] -> out[C][R]
  __shared__ float tile[32][33];
  const int R = HDIM, C = EDIM;
  const int c0 = blockIdx.x * 32;
  const int r0 = blockIdx.y * 32;
  const int tx = threadIdx.x;        // 0..31
  const int ty = threadIdx.y;        // 0..7
#pragma unroll
  for (int i = 0; i < 4; ++i) {
    int r = r0 + ty + i * 8;
    int c = c0 + tx;
    if (r < R && c < C) tile[ty + i * 8][tx] = in[r * C + c];
  }
  __syncthreads();
#pragma unroll
  for (int i = 0; i < 4; ++i) {
    int c = c0 + ty + i * 8;
    int r = r0 + tx;
    if (c < C && r < R) out[c * R + r] = tile[tx][ty + i * 8];
  }
}

// ---------------- Kernel B: fused MLP (relu(y@w1.T+b1)) @ w2.T + b2 ---------
// RB batch rows per block. Thread j computes h[j], h[j+256] for RB rows
// (coalesced w1t reads; y broadcast from LDS). Then per-wave reduce for the
// 5 outputs of its row.
#define RB 4
__global__ __launch_bounds__(256) void mlp_kernel(
    const float* __restrict__ y, const float* __restrict__ w1t,
    const float* __restrict__ b1, const float* __restrict__ w2,
    const float* __restrict__ b2, float* __restrict__ out) {
  const int b0 = blockIdx.x * RB;
  __shared__ float sy[RB][304];
  __shared__ float sh[RB][HDIM];

  const int tid = threadIdx.x;

  for (int i = tid; i < RB * EDIM; i += 256) {
    int r = i / EDIM, k = i - r * EDIM;
    sy[r][k] = y[(size_t)(b0 + r) * EDIM + k];
  }
  __syncthreads();

  float acc[RB][2];
#pragma unroll
  for (int r = 0; r < RB; ++r) { acc[r][0] = 0.f; acc[r][1] = 0.f; }

  for (int k = 0; k < EDIM; ++k) {
    const float wv0 = w1t[k * HDIM + tid];
    const float wv1 = w1t[k * HDIM + tid + 256];
#pragma unroll
    for (int r = 0; r < RB; ++r) {
      const float yv = sy[r][k];
      acc[r][0] = fmaf(wv0, yv, acc[r][0]);
      acc[r][1] = fmaf(wv1, yv, acc[r][1]);
    }
  }

  const float bb0 = b1[tid];
  const float bb1 = b1[tid + 256];
#pragma unroll
  for (int r = 0; r < RB; ++r) {
    sh[r][tid] = fmaxf(acc[r][0] + bb0, 0.f);
    sh[r][tid + 256] = fmaxf(acc[r][1] + bb1, 0.f);
  }
  __syncthreads();

  const int wave = tid >> 6;  // wave r handles batch row b0+r
  const int lane = tid & 63;
#pragma unroll
  for (int o = 0; o < ODIM; ++o) {
    float p = 0.f;
    for (int j = lane; j < HDIM; j += 64) p = fmaf(w2[o * HDIM + j], sh[wave][j], p);
#pragma unroll
    for (int off = 32; off > 0; off >>= 1) p += __shfl_down(p, off);
    if (lane == 0) out[(size_t)(b0 + wave) * ODIM + o] = p + b2[o];
  }
}

extern "C" void kernel_launch(void* const* d_in, const int* in_sizes, int n_in,
                              void* d_out, int out_size, void* d_ws, size_t ws_size,
                              hipStream_t stream) {
  const int* x = (const int*)d_in[0];          // [1024, 512] int32
  const float* weight = (const float*)d_in[1]; // [100000, 300]
  const float* w1 = (const float*)d_in[2];     // [512, 300]
  const float* b1 = (const float*)d_in[3];     // [512]
  const float* w2 = (const float*)d_in[4];     // [5, 512]
  const float* b2 = (const float*)d_in[5];     // [5]
  float* out = (float*)d_out;                  // [1024, 5]

  float* y = (float*)d_ws;                     // [1024, 300]
  float* w1t = y + (size_t)BATCH * EDIM;       // [300, 512]

  embed_sum_kernel<<<BATCH, 256, 0, stream>>>(x, weight, y);

  dim3 tb(32, 8);
  dim3 tg((EDIM + 31) / 32, HDIM / 32);
  transpose_kernel<<<tg, tb, 0, stream>>>(w1, w1t);

  mlp_kernel<<<BATCH / RB, 256, 0, stream>>>(y, w1t, b1, w2, b2, out);
}

// Round 2
// 92.533 us; speedup vs baseline: 1.0229x; 1.0229x over previous
//
#include <hip/hip_runtime.h>
#include <hip/hip_bf16.h>

#define SEQ_L 512
#define EDIM 300
#define HDIM 512
#define ODIM 5
#define BATCH 1024
#define CHUNK 256
#define NCH (SEQ_L / CHUNK)  // 2 chunks per row
#define RB 4

// ---------------- Kernel A: per-(row,chunk) partial embedding sum -----------
// Padding is a zero SUFFIX (reference masks pos >= len to token 0), so the
// nonzero tokens are a prefix of each chunk: loop t < n_c, no divergence.
// The padding contribution (512-len)*weight[0] is added analytically in the
// MLP kernel. 2048 blocks = 8 blocks/CU -> full 32 waves/CU residency.
// 4-deep manual prefetch: 8 independent global loads in flight per wave.
__global__ __launch_bounds__(256) void embed_chunk_kernel(
    const int* __restrict__ x, const float* __restrict__ weight,
    float* __restrict__ part, int* __restrict__ cnt) {
  const int blk = blockIdx.x;
  const int b = blk >> 1;
  const int c = blk & 1;
  __shared__ int stok[CHUNK];
  __shared__ int s_zero;
  __shared__ float sred[4][304];

  const int tid = threadIdx.x;
  if (tid == 0) s_zero = 0;
  const int tok = x[b * SEQ_L + c * CHUNK + tid];
  stok[tid] = tok;
  __syncthreads();
  if (tok == 0) atomicAdd(&s_zero, 1);  // compiler coalesces per-wave
  __syncthreads();
  const int n_c = CHUNK - s_zero;  // nonzero prefix length of this chunk

  const int wave = tid >> 6;
  const int lane = tid & 63;
  const bool hasS = lane < (EDIM - 256);  // lanes 0..43 own float 256+lane

  float4 acc = make_float4(0.f, 0.f, 0.f, 0.f);
  float accS = 0.f;

  int t = wave;
  for (; t + 12 < n_c; t += 16) {
    const int i0 = stok[t], i1 = stok[t + 4], i2 = stok[t + 8], i3 = stok[t + 12];
    const float* r0 = weight + (size_t)i0 * EDIM;
    const float* r1 = weight + (size_t)i1 * EDIM;
    const float* r2 = weight + (size_t)i2 * EDIM;
    const float* r3 = weight + (size_t)i3 * EDIM;
    const float4 v0 = *reinterpret_cast<const float4*>(r0 + 4 * lane);
    const float4 v1 = *reinterpret_cast<const float4*>(r1 + 4 * lane);
    const float4 v2 = *reinterpret_cast<const float4*>(r2 + 4 * lane);
    const float4 v3 = *reinterpret_cast<const float4*>(r3 + 4 * lane);
    float s0 = 0.f, s1 = 0.f, s2 = 0.f, s3 = 0.f;
    if (hasS) {
      s0 = r0[256 + lane]; s1 = r1[256 + lane];
      s2 = r2[256 + lane]; s3 = r3[256 + lane];
    }
    acc.x += v0.x + v1.x + v2.x + v3.x;
    acc.y += v0.y + v1.y + v2.y + v3.y;
    acc.z += v0.z + v1.z + v2.z + v3.z;
    acc.w += v0.w + v1.w + v2.w + v3.w;
    accS += s0 + s1 + s2 + s3;
  }
  for (; t < n_c; t += 4) {
    const int i = stok[t];
    const float* r = weight + (size_t)i * EDIM;
    const float4 v = *reinterpret_cast<const float4*>(r + 4 * lane);
    acc.x += v.x; acc.y += v.y; acc.z += v.z; acc.w += v.w;
    if (hasS) accS += r[256 + lane];
  }

  *reinterpret_cast<float4*>(&sred[wave][4 * lane]) = acc;
  if (hasS) sred[wave][256 + lane] = accS;
  __syncthreads();

  for (int d = tid; d < EDIM; d += 256) {
    part[(size_t)blk * EDIM + d] =
        sred[0][d] + sred[1][d] + sred[2][d] + sred[3][d];
  }
  if (tid == 0) cnt[blk] = n_c;
}

// ---------------- Kernel T: transpose w1 [512,300] -> w1t [300,512] ---------
__global__ __launch_bounds__(256) void transpose_kernel(
    const float* __restrict__ in, float* __restrict__ out) {
  __shared__ float tile[32][33];
  const int R = HDIM, C = EDIM;
  const int c0 = blockIdx.x * 32;
  const int r0 = blockIdx.y * 32;
  const int tx = threadIdx.x;
  const int ty = threadIdx.y;
#pragma unroll
  for (int i = 0; i < 4; ++i) {
    int r = r0 + ty + i * 8;
    int c = c0 + tx;
    if (r < R && c < C) tile[ty + i * 8][tx] = in[r * C + c];
  }
  __syncthreads();
#pragma unroll
  for (int i = 0; i < 4; ++i) {
    int c = c0 + ty + i * 8;
    int r = r0 + tx;
    if (c < C && r < R) out[c * R + r] = tile[tx][ty + i * 8];
  }
}

// ---------------- Kernel B: fused reduce + MLP ------------------------------
// Reduce chunk partials + analytic padding term + divide by length, then
// relu(y@w1.T+b1) @ w2.T + b2. RB=4 rows per block.
__global__ __launch_bounds__(256) void mlp_kernel(
    const float* __restrict__ part, const int* __restrict__ cnt,
    const float* __restrict__ w0,  // weight row 0 (padding embedding)
    const float* __restrict__ w1t, const float* __restrict__ b1,
    const float* __restrict__ w2, const float* __restrict__ b2,
    float* __restrict__ out) {
  const int b0 = blockIdx.x * RB;
  __shared__ float sy[RB][304];
  __shared__ float sh[RB][HDIM];
  __shared__ float slen[RB];

  const int tid = threadIdx.x;
  if (tid < RB) {
    int len = cnt[(b0 + tid) * NCH + 0] + cnt[(b0 + tid) * NCH + 1];
    slen[tid] = (float)len;  // len >= 1 guaranteed (lens in [1, 512])
  }
  __syncthreads();

  for (int i = tid; i < RB * EDIM; i += 256) {
    const int r = i / EDIM, d = i - r * EDIM;
    const size_t base = (size_t)(b0 + r) * NCH * EDIM;
    float s = part[base + d] + part[base + EDIM + d];
    const float len = slen[r];
    s += ((float)SEQ_L - len) * w0[d];
    sy[r][d] = s / len;
  }
  __syncthreads();

  float acc[RB][2];
#pragma unroll
  for (int r = 0; r < RB; ++r) { acc[r][0] = 0.f; acc[r][1] = 0.f; }

  for (int k = 0; k < EDIM; ++k) {
    const float wv0 = w1t[k * HDIM + tid];
    const float wv1 = w1t[k * HDIM + tid + 256];
#pragma unroll
    for (int r = 0; r < RB; ++r) {
      const float yv = sy[r][k];
      acc[r][0] = fmaf(wv0, yv, acc[r][0]);
      acc[r][1] = fmaf(wv1, yv, acc[r][1]);
    }
  }

  const float bb0 = b1[tid];
  const float bb1 = b1[tid + 256];
#pragma unroll
  for (int r = 0; r < RB; ++r) {
    sh[r][tid] = fmaxf(acc[r][0] + bb0, 0.f);
    sh[r][tid + 256] = fmaxf(acc[r][1] + bb1, 0.f);
  }
  __syncthreads();

  const int wave = tid >> 6;
  const int lane = tid & 63;
#pragma unroll
  for (int o = 0; o < ODIM; ++o) {
    float p = 0.f;
    for (int j = lane; j < HDIM; j += 64)
      p = fmaf(w2[o * HDIM + j], sh[wave][j], p);
#pragma unroll
    for (int off = 32; off > 0; off >>= 1) p += __shfl_down(p, off);
    if (lane == 0) out[(size_t)(b0 + wave) * ODIM + o] = p + b2[o];
  }
}

extern "C" void kernel_launch(void* const* d_in, const int* in_sizes, int n_in,
                              void* d_out, int out_size, void* d_ws, size_t ws_size,
                              hipStream_t stream) {
  const int* x = (const int*)d_in[0];          // [1024, 512] int32
  const float* weight = (const float*)d_in[1]; // [100000, 300]
  const float* w1 = (const float*)d_in[2];     // [512, 300]
  const float* b1 = (const float*)d_in[3];     // [512]
  const float* w2 = (const float*)d_in[4];     // [5, 512]
  const float* b2 = (const float*)d_in[5];     // [5]
  float* out = (float*)d_out;                  // [1024, 5]

  // ws layout: part [2048*300] f32 | w1t [300*512] f32 | cnt [2048] i32
  float* part = (float*)d_ws;
  float* w1t = part + (size_t)BATCH * NCH * EDIM;
  int* cnt = (int*)(w1t + (size_t)EDIM * HDIM);

  dim3 tb(32, 8);
  dim3 tg((EDIM + 31) / 32, HDIM / 32);
  transpose_kernel<<<tg, tb, 0, stream>>>(w1, w1t);

  embed_chunk_kernel<<<BATCH * NCH, 256, 0, stream>>>(x, weight, part, cnt);

  mlp_kernel<<<BATCH / RB, 256, 0, stream>>>(part, cnt, weight, w1t, b1, w2,
                                             b2, out);
}

// Round 3
// 91.149 us; speedup vs baseline: 1.0384x; 1.0152x over previous
//
#include <hip/hip_runtime.h>
#include <hip/hip_bf16.h>

#define SEQ_L 512
#define EDIM 300
#define HDIM 512
#define ODIM 5
#define BATCH 1024
#define NCH 4
#define CPOS (SEQ_L / NCH)  // 128 interleaved positions per chunk
#define RB 8

// ---------------- Kernel A: per-(row,chunk) partial embedding sum -----------
// Interleaved chunking: block (b,c) handles positions p = c + 4*i, i<128.
// Zeros are a suffix in i as well (p >= len <=> i >= n_c), so every chunk of
// a row carries ~len/4 nonzero tokens -> balanced blocks. 4096 blocks give
// the scheduler backfill headroom. Depth-6 manual prefetch = 12 independent
// global loads in flight per wave; launch_bounds(256,8) pins VGPR<=64 so all
// 8 waves/SIMD stay resident.
__global__ __launch_bounds__(256, 8) void embed_chunk_kernel(
    const int* __restrict__ x, const float* __restrict__ weight,
    float* __restrict__ part, int* __restrict__ cnt) {
  const int blk = blockIdx.x;
  const int b = blk >> 2;
  const int c = blk & 3;
  __shared__ int stok[CPOS];
  __shared__ int s_nz;
  __shared__ float sred[4][304];

  const int tid = threadIdx.x;
  if (tid == 0) s_nz = 0;
  __syncthreads();

  int tok = 0;
  if (tid < CPOS) {
    tok = x[b * SEQ_L + c + NCH * tid];
    stok[tid] = tok;
  }
  const unsigned long long nzmask = __ballot(tid < CPOS && tok != 0);
  if (tid < CPOS && (tid & 63) == 0) atomicAdd(&s_nz, __popcll(nzmask));
  __syncthreads();
  const int n_c = s_nz;  // nonzero prefix length (in i) of this chunk

  const int wave = tid >> 6;
  const int lane = tid & 63;
  const bool hasS = lane < (EDIM - 256);  // lanes 0..43 own float 256+lane

  float4 acc = make_float4(0.f, 0.f, 0.f, 0.f);
  float accS = 0.f;

  int i = wave;
  for (; i + 20 < n_c; i += 24) {  // waves stride 4; window = 6 tokens
    const float* r0 = weight + (size_t)stok[i] * EDIM;
    const float* r1 = weight + (size_t)stok[i + 4] * EDIM;
    const float* r2 = weight + (size_t)stok[i + 8] * EDIM;
    const float* r3 = weight + (size_t)stok[i + 12] * EDIM;
    const float* r4 = weight + (size_t)stok[i + 16] * EDIM;
    const float* r5 = weight + (size_t)stok[i + 20] * EDIM;
    const float4 v0 = *reinterpret_cast<const float4*>(r0 + 4 * lane);
    const float4 v1 = *reinterpret_cast<const float4*>(r1 + 4 * lane);
    const float4 v2 = *reinterpret_cast<const float4*>(r2 + 4 * lane);
    const float4 v3 = *reinterpret_cast<const float4*>(r3 + 4 * lane);
    const float4 v4 = *reinterpret_cast<const float4*>(r4 + 4 * lane);
    const float4 v5 = *reinterpret_cast<const float4*>(r5 + 4 * lane);
    float s0 = 0.f, s1 = 0.f, s2 = 0.f, s3 = 0.f, s4 = 0.f, s5 = 0.f;
    if (hasS) {
      s0 = r0[256 + lane]; s1 = r1[256 + lane]; s2 = r2[256 + lane];
      s3 = r3[256 + lane]; s4 = r4[256 + lane]; s5 = r5[256 + lane];
    }
    acc.x += (v0.x + v1.x) + (v2.x + v3.x) + (v4.x + v5.x);
    acc.y += (v0.y + v1.y) + (v2.y + v3.y) + (v4.y + v5.y);
    acc.z += (v0.z + v1.z) + (v2.z + v3.z) + (v4.z + v5.z);
    acc.w += (v0.w + v1.w) + (v2.w + v3.w) + (v4.w + v5.w);
    accS += (s0 + s1) + (s2 + s3) + (s4 + s5);
  }
  for (; i < n_c; i += 4) {
    const float* r = weight + (size_t)stok[i] * EDIM;
    const float4 v = *reinterpret_cast<const float4*>(r + 4 * lane);
    acc.x += v.x; acc.y += v.y; acc.z += v.z; acc.w += v.w;
    if (hasS) accS += r[256 + lane];
  }

  *reinterpret_cast<float4*>(&sred[wave][4 * lane]) = acc;
  if (hasS) sred[wave][256 + lane] = accS;
  __syncthreads();

  for (int d = tid; d < EDIM; d += 256) {
    part[(size_t)blk * EDIM + d] =
        sred[0][d] + sred[1][d] + sred[2][d] + sred[3][d];
  }
  if (tid == 0) cnt[blk] = n_c;
}

// ---------------- Kernel T: transpose w1 [512,300] -> w1t [300,512] ---------
__global__ __launch_bounds__(256) void transpose_kernel(
    const float* __restrict__ in, float* __restrict__ out) {
  __shared__ float tile[32][33];
  const int R = HDIM, C = EDIM;
  const int c0 = blockIdx.x * 32;
  const int r0 = blockIdx.y * 32;
  const int tx = threadIdx.x;
  const int ty = threadIdx.y;
#pragma unroll
  for (int i = 0; i < 4; ++i) {
    int r = r0 + ty + i * 8;
    int c = c0 + tx;
    if (r < R && c < C) tile[ty + i * 8][tx] = in[r * C + c];
  }
  __syncthreads();
#pragma unroll
  for (int i = 0; i < 4; ++i) {
    int c = c0 + ty + i * 8;
    int r = r0 + tx;
    if (c < C && r < R) out[c * R + r] = tile[tx][ty + i * 8];
  }
}

// ---------------- Kernel B: fused reduce + MLP ------------------------------
// Reduce NCH chunk partials + analytic padding term + divide by length, then
// relu(y@w1.T+b1) @ w2.T + b2. RB=8 rows per block (halves w1t re-reads vs 4).
__global__ __launch_bounds__(256) void mlp_kernel(
    const float* __restrict__ part, const int* __restrict__ cnt,
    const float* __restrict__ w0,  // weight row 0 (padding embedding)
    const float* __restrict__ w1t, const float* __restrict__ b1,
    const float* __restrict__ w2, const float* __restrict__ b2,
    float* __restrict__ out) {
  const int b0 = blockIdx.x * RB;
  __shared__ float sy[RB][304];
  __shared__ float sh[RB][HDIM];
  __shared__ float slen[RB];

  const int tid = threadIdx.x;
  if (tid < RB) {
    const int* cb = cnt + (b0 + tid) * NCH;
    slen[tid] = (float)(cb[0] + cb[1] + cb[2] + cb[3]);  // len >= 1
  }
  __syncthreads();

  for (int i = tid; i < RB * EDIM; i += 256) {
    const int r = i / EDIM, d = i - r * EDIM;
    const float* pb = part + (size_t)(b0 + r) * NCH * EDIM;
    float s = (pb[d] + pb[EDIM + d]) + (pb[2 * EDIM + d] + pb[3 * EDIM + d]);
    const float len = slen[r];
    s += ((float)SEQ_L - len) * w0[d];
    sy[r][d] = s / len;
  }
  __syncthreads();

  float acc[RB][2];
#pragma unroll
  for (int r = 0; r < RB; ++r) { acc[r][0] = 0.f; acc[r][1] = 0.f; }

  for (int k = 0; k < EDIM; ++k) {
    const float wv0 = w1t[k * HDIM + tid];
    const float wv1 = w1t[k * HDIM + tid + 256];
#pragma unroll
    for (int r = 0; r < RB; ++r) {
      const float yv = sy[r][k];
      acc[r][0] = fmaf(wv0, yv, acc[r][0]);
      acc[r][1] = fmaf(wv1, yv, acc[r][1]);
    }
  }

  const float bb0 = b1[tid];
  const float bb1 = b1[tid + 256];
#pragma unroll
  for (int r = 0; r < RB; ++r) {
    sh[r][tid] = fmaxf(acc[r][0] + bb0, 0.f);
    sh[r][tid + 256] = fmaxf(acc[r][1] + bb1, 0.f);
  }
  __syncthreads();

  const int wave = tid >> 6;
  const int lane = tid & 63;
  for (int rr = wave; rr < RB; rr += 4) {
#pragma unroll
    for (int o = 0; o < ODIM; ++o) {
      float p = 0.f;
      for (int j = lane; j < HDIM; j += 64)
        p = fmaf(w2[o * HDIM + j], sh[rr][j], p);
#pragma unroll
      for (int off = 32; off > 0; off >>= 1) p += __shfl_down(p, off);
      if (lane == 0) out[(size_t)(b0 + rr) * ODIM + o] = p + b2[o];
    }
  }
}

extern "C" void kernel_launch(void* const* d_in, const int* in_sizes, int n_in,
                              void* d_out, int out_size, void* d_ws, size_t ws_size,
                              hipStream_t stream) {
  const int* x = (const int*)d_in[0];          // [1024, 512] int32
  const float* weight = (const float*)d_in[1]; // [100000, 300]
  const float* w1 = (const float*)d_in[2];     // [512, 300]
  const float* b1 = (const float*)d_in[3];     // [512]
  const float* w2 = (const float*)d_in[4];     // [5, 512]
  const float* b2 = (const float*)d_in[5];     // [5]
  float* out = (float*)d_out;                  // [1024, 5]

  // ws layout: part [4096*300] f32 | w1t [300*512] f32 | cnt [4096] i32
  float* part = (float*)d_ws;
  float* w1t = part + (size_t)BATCH * NCH * EDIM;
  int* cnt = (int*)(w1t + (size_t)EDIM * HDIM);

  dim3 tb(32, 8);
  dim3 tg((EDIM + 31) / 32, HDIM / 32);
  transpose_kernel<<<tg, tb, 0, stream>>>(w1, w1t);

  embed_chunk_kernel<<<BATCH * NCH, 256, 0, stream>>>(x, weight, part, cnt);

  mlp_kernel<<<BATCH / RB, 256, 0, stream>>>(part, cnt, weight, w1t, b1, w2,
                                             b2, out);
}